// Round 1
// 547.495 us; speedup vs baseline: 1.0688x; 1.0688x over previous
//
#include <hip/hip_runtime.h>
#include <hip/hip_fp16.h>
#include <math.h>

#define B_   16
#define CI   2048
#define NI   16
#define CJ   64
#define NJ   32
#define JM   2048      // CJ*NJ
#define CH   8         // i's per block
#define NCH  256       // i-chunks = CI/CH
#define ALPHA 8.0f

// ---------------------------------------------------------------------------
// R5 pass-0 (full path only): ONE block per ichunk handles ALL 16 b's, so each
// w element is fetched from far memory exactly once (R4's bhalf split read w
// twice -> 512 MB far reads; this is 256 MB). 256 blocks x 1024 thr.
// Thread = (bh 0..3) x (jg 0..255); each thread: 4 b's x 8 jm.
// Far traffic: 256 (w) + 2 (x) + 134 (U16 wr) + 33.5 (PART wr) = ~425 MB.
// ---------------------------------------------------------------------------
__global__ __launch_bounds__(1024)
void pass0_full(const float* __restrict__ x, const float* __restrict__ w,
                float* __restrict__ part, __half* __restrict__ U16)
{
    __shared__ float xs[CH][16][NI];   // 8 KB staged inputs (all 16 b's)

    const int ichunk = blockIdx.x;
    const int i0     = ichunk * CH;
    const int tid    = threadIdx.x;
    const int bh     = tid >> 8;       // 0..3
    const int jg     = tid & 255;
    const int jm0    = jg * 8;

    if (tid < 512) {
        const int f  = tid * 4;
        const int n  = f & 15;
        const int b  = (f >> 4) & 15;
        const int ci = f >> 8;
        *(float4*)(&xs[ci][b][n]) =
            *(const float4*)(x + ((size_t)b * CI + (i0 + ci)) * NI + n);
    }

    float acc[4][8];
#pragma unroll
    for (int bb = 0; bb < 4; ++bb)
#pragma unroll
        for (int k = 0; k < 8; ++k) acc[bb][k] = 0.0f;

    __syncthreads();

    for (int ci = 0; ci < CH; ++ci) {
        const int i = i0 + ci;

        float u[4][8];
#pragma unroll
        for (int bb = 0; bb < 4; ++bb)
#pragma unroll
            for (int k = 0; k < 8; ++k) u[bb][k] = 0.0f;

        const float* wrow = w + (size_t)i * (NI * JM) + jm0;
#pragma unroll
        for (int n = 0; n < NI; ++n) {
            const float4 w0 = *(const float4*)(wrow + (size_t)n * JM);
            const float4 w1 = *(const float4*)(wrow + (size_t)n * JM + 4);
#pragma unroll
            for (int bb = 0; bb < 4; ++bb) {
                const float xv = xs[ci][bh * 4 + bb][n];
                u[bb][0] = fmaf(xv, w0.x, u[bb][0]);
                u[bb][1] = fmaf(xv, w0.y, u[bb][1]);
                u[bb][2] = fmaf(xv, w0.z, u[bb][2]);
                u[bb][3] = fmaf(xv, w0.w, u[bb][3]);
                u[bb][4] = fmaf(xv, w1.x, u[bb][4]);
                u[bb][5] = fmaf(xv, w1.y, u[bb][5]);
                u[bb][6] = fmaf(xv, w1.z, u[bb][6]);
                u[bb][7] = fmaf(xv, w1.w, u[bb][7]);
            }
        }

#pragma unroll
        for (int bb = 0; bb < 4; ++bb) {
#pragma unroll
            for (int k = 0; k < 8; ++k) acc[bb][k] += u[bb][k];
            const int b = bh * 4 + bb;
            union { uint4 q; __half h[8]; } pk;
#pragma unroll
            for (int k = 0; k < 8; ++k) pk.h[k] = __float2half(u[bb][k]);
            *(uint4*)(U16 + ((size_t)b * CI + i) * JM + jm0) = pk.q;
        }
    }

#pragma unroll
    for (int bb = 0; bb < 4; ++bb) {
        const int b = bh * 4 + bb;
        float* dst = part + ((size_t)b * NCH + ichunk) * JM + jm0;
        *(float4*)(dst)     =
            make_float4(acc[bb][0], acc[bb][1], acc[bb][2], acc[bb][3]);
        *(float4*)(dst + 4) =
            make_float4(acc[bb][4], acc[bb][5], acc[bb][6], acc[bb][7]);
    }
}

// ---------------------------------------------------------------------------
// Legacy pass kernel (fallback paths only; unchanged from R4).
// ---------------------------------------------------------------------------
template <int PASS, bool ATOMIC, bool STOREU>
__global__ __launch_bounds__(1024)
void pass_kernel(const float* __restrict__ x, const float* __restrict__ w,
                 const float* __restrict__ vprev, float* __restrict__ a0,
                 float* __restrict__ sout, __half* __restrict__ U16)
{
    __shared__ float xs[CH][8][NI];    // 4 KB staged inputs (8 b's)
    __shared__ float Ls[8][CJ];        // 2 KB logits
    __shared__ float smax[8], sinv[8];

    const int idx    = blockIdx.x;
    const int xcd    = idx & 7;
    const int bhalf  = (idx >> 3) & 1;
    const int slot   = idx >> 4;
    const int ichunk = slot * 8 + xcd;
    const int i0     = ichunk * CH;
    const int b0     = bhalf * 8;

    const int tid  = threadIdx.x;
    const int bh   = tid >> 8;        // 0..3
    const int jg   = tid & 255;
    const int jm0  = jg * 8;
    const int jcol = jg >> 2;         // j in 0..63

    if (tid < 256) {
        const int f  = tid * 4;
        const int n  = f & 15;
        const int bg = (f >> 4) & 7;
        const int ci = f >> 7;
        *(float4*)(&xs[ci][bg][n]) =
            *(const float4*)(x + ((size_t)(b0 + bg) * CI + (i0 + ci)) * NI + n);
    }

    float acc[2][8];
#pragma unroll
    for (int bb = 0; bb < 2; ++bb)
#pragma unroll
        for (int k = 0; k < 8; ++k) acc[bb][k] = 0.0f;

    __syncthreads();

    for (int ci = 0; ci < CH; ++ci) {
        const int i = i0 + ci;

        float u[2][8];
#pragma unroll
        for (int bb = 0; bb < 2; ++bb)
#pragma unroll
            for (int k = 0; k < 8; ++k) u[bb][k] = 0.0f;

        const float* wrow = w + (size_t)i * (NI * JM) + jm0;
#pragma unroll
        for (int n = 0; n < NI; ++n) {
            const float4 w0 = *(const float4*)(wrow + (size_t)n * JM);
            const float4 w1 = *(const float4*)(wrow + (size_t)n * JM + 4);
#pragma unroll
            for (int bb = 0; bb < 2; ++bb) {
                const float xv = xs[ci][bh * 2 + bb][n];
                u[bb][0] = fmaf(xv, w0.x, u[bb][0]);
                u[bb][1] = fmaf(xv, w0.y, u[bb][1]);
                u[bb][2] = fmaf(xv, w0.z, u[bb][2]);
                u[bb][3] = fmaf(xv, w0.w, u[bb][3]);
                u[bb][4] = fmaf(xv, w1.x, u[bb][4]);
                u[bb][5] = fmaf(xv, w1.y, u[bb][5]);
                u[bb][6] = fmaf(xv, w1.z, u[bb][6]);
                u[bb][7] = fmaf(xv, w1.w, u[bb][7]);
            }
        }

        if (PASS == 0) {
#pragma unroll
            for (int bb = 0; bb < 2; ++bb)
#pragma unroll
                for (int k = 0; k < 8; ++k) acc[bb][k] += u[bb][k];
            if (STOREU) {
#pragma unroll
                for (int bb = 0; bb < 2; ++bb) {
                    const int b = b0 + bh * 2 + bb;
                    union { uint4 q; __half h[8]; } pk;
#pragma unroll
                    for (int k = 0; k < 8; ++k) pk.h[k] = __float2half(u[bb][k]);
                    *(uint4*)(U16 + ((size_t)b * CI + i) * JM + jm0) = pk.q;
                }
            }
        } else {
            float ap[2];
#pragma unroll
            for (int bb = 0; bb < 2; ++bb) {
                const int b = b0 + bh * 2 + bb;
                const float4 v0 = *(const float4*)(vprev + (size_t)b * JM + jm0);
                const float4 v1 = *(const float4*)(vprev + (size_t)b * JM + jm0 + 4);
                float t = u[bb][0] * v0.x + u[bb][1] * v0.y
                        + u[bb][2] * v0.z + u[bb][3] * v0.w
                        + u[bb][4] * v1.x + u[bb][5] * v1.y
                        + u[bb][6] * v1.z + u[bb][7] * v1.w;
                t += __shfl_xor(t, 1);
                t += __shfl_xor(t, 2);
                ap[bb] = t;
            }

            float L[2];
#pragma unroll
            for (int bb = 0; bb < 2; ++bb) {
                if (PASS == 1) {
                    L[bb] = ap[bb];
                } else {
                    const int b = b0 + bh * 2 + bb;
                    L[bb] = ap[bb] + a0[((size_t)b * CI + i) * CJ + jcol];
                }
            }
            if ((jg & 3) == 0) {
#pragma unroll
                for (int bb = 0; bb < 2; ++bb) {
                    const int bg = bh * 2 + bb;
                    Ls[bg][jcol] = L[bb];
                    if (PASS == 1)
                        a0[((size_t)(b0 + bg) * CI + i) * CJ + jcol] = ap[bb];
                }
            }
            __syncthreads();

            if (tid < 256) {
                const int rb = tid >> 5, rj = tid & 31;
                const float x1 = Ls[rb][rj];
                const float x2 = Ls[rb][rj + 32];
                float mx = fmaxf(x1, x2);
#pragma unroll
                for (int s2 = 1; s2 < 32; s2 <<= 1)
                    mx = fmaxf(mx, __shfl_xor(mx, s2));
                float ex = __expf(ALPHA * (x1 - mx)) + __expf(ALPHA * (x2 - mx));
#pragma unroll
                for (int s2 = 1; s2 < 32; s2 <<= 1)
                    ex += __shfl_xor(ex, s2);
                if (rj == 0) { smax[rb] = mx; sinv[rb] = 64.0f / ex; }
            }
            __syncthreads();

#pragma unroll
            for (int bb = 0; bb < 2; ++bb) {
                const int bg = bh * 2 + bb;
                const float c = __expf(ALPHA * (L[bb] - smax[bg])) * sinv[bg];
#pragma unroll
                for (int k = 0; k < 8; ++k)
                    acc[bb][k] = fmaf(c, u[bb][k], acc[bb][k]);
            }
        }
    }

    if (ATOMIC) {
#pragma unroll
        for (int bb = 0; bb < 2; ++bb) {
            const int b = b0 + bh * 2 + bb;
#pragma unroll
            for (int k = 0; k < 8; ++k)
                unsafeAtomicAdd(sout + (size_t)b * JM + jm0 + k, acc[bb][k]);
        }
    } else {
#pragma unroll
        for (int bb = 0; bb < 2; ++bb) {
            const int b = b0 + bh * 2 + bb;
            float* dst = sout + ((size_t)b * NCH + ichunk) * JM + jm0;
            *(float4*)(dst)     =
                make_float4(acc[bb][0], acc[bb][1], acc[bb][2], acc[bb][3]);
            *(float4*)(dst + 4) =
                make_float4(acc[bb][4], acc[bb][5], acc[bb][6], acc[bb][7]);
        }
    }
}

// ---------------------------------------------------------------------------
// R5 routing pass over cached fp16 u. Fully register-resident:
//  - lane l = capsule j; v[b][l][0..31] loop-invariant -> vr[32] registers
//    (R4 staged v in LDS -> 32 ds_read_b32 per i; now zero LDS, no barrier).
//  - 2-deep software pipeline: prefetch (ii+1)'s 64 B while computing ii.
//  - a0 eliminated: after r=1, b = v0*u + v1*u = (v0+v1)*u, so pass 2 folds
//    v0+v1 into vr at load (TWO=true). No a0 store/load at all.
// grid: 1024 blocks = b(16) x ig(64); 256 thr = 4 waves x 8 i.
// PART row per wave: p = ig*4 + wv (256 partials, same reduce kernel).
// ---------------------------------------------------------------------------
template <bool TWO>
__global__ __launch_bounds__(256)
void route_kernel(const __half* __restrict__ U16, const float* __restrict__ va,
                  const float* __restrict__ vb, float* __restrict__ part)
{
    const int tid = threadIdx.x;
    const int b   = blockIdx.x >> 6;
    const int ig  = blockIdx.x & 63;
    const int wv  = tid >> 6;
    const int l   = tid & 63;       // j = l

    float vr[32];
#pragma unroll
    for (int q = 0; q < 8; ++q) {
        const float4 f = *(const float4*)(va + (size_t)b * JM + l * 32 + q * 4);
        vr[q * 4 + 0] = f.x; vr[q * 4 + 1] = f.y;
        vr[q * 4 + 2] = f.z; vr[q * 4 + 3] = f.w;
    }
    if (TWO) {
#pragma unroll
        for (int q = 0; q < 8; ++q) {
            const float4 f = *(const float4*)(vb + (size_t)b * JM + l * 32 + q * 4);
            vr[q * 4 + 0] += f.x; vr[q * 4 + 1] += f.y;
            vr[q * 4 + 2] += f.z; vr[q * 4 + 3] += f.w;
        }
    }

    float acc[32];
#pragma unroll
    for (int m = 0; m < 32; ++m) acc[m] = 0.0f;

    const __half* up0 = U16 + ((size_t)b * CI + ig * 32 + wv * 8) * JM + l * 32;

    union F4H { float4 f; __half2 h2[4]; };
    F4H cur[4], nxt[4];
#pragma unroll
    for (int q = 0; q < 4; ++q)
        cur[q].f = *(const float4*)(up0 + q * 8);

#pragma unroll
    for (int ii = 0; ii < 8; ++ii) {
        if (ii < 7) {
            const __half* upn = up0 + (size_t)(ii + 1) * JM;
#pragma unroll
            for (int q = 0; q < 4; ++q)
                nxt[q].f = *(const float4*)(upn + q * 8);
        }

        // agreement: ap = sum_m vr[m] * u[b,i,j=l,m]
        float ap = 0.0f;
#pragma unroll
        for (int q = 0; q < 4; ++q)
#pragma unroll
            for (int p = 0; p < 4; ++p) {
                const float2 uf = __half22float2(cur[q].h2[p]);
                const int m = q * 8 + p * 2;
                ap = fmaf(vr[m],     uf.x, ap);
                ap = fmaf(vr[m + 1], uf.y, ap);
            }

        // softmax over 64 j (whole wave)
        float mx = ap;
#pragma unroll
        for (int d = 1; d < 64; d <<= 1)
            mx = fmaxf(mx, __shfl_xor(mx, d));
        const float e = __expf(ALPHA * (ap - mx));
        float se = e;
#pragma unroll
        for (int d = 1; d < 64; d <<= 1)
            se += __shfl_xor(se, d);
        const float c = e * (64.0f / se);

#pragma unroll
        for (int q = 0; q < 4; ++q)
#pragma unroll
            for (int p = 0; p < 4; ++p) {
                const float2 uf = __half22float2(cur[q].h2[p]);
                const int m = q * 8 + p * 2;
                acc[m]     = fmaf(c, uf.x, acc[m]);
                acc[m + 1] = fmaf(c, uf.y, acc[m + 1]);
            }

#pragma unroll
        for (int q = 0; q < 4; ++q) cur[q] = nxt[q];
    }

    // PART[b][p][jm], p = ig*4 + wv ; lane writes its 32 m's (j = l)
    float* dst = part + ((size_t)b * NCH + (ig * 4 + wv)) * JM + l * 32;
#pragma unroll
    for (int q = 0; q < 8; ++q)
        *(float4*)(dst + q * 4) =
            make_float4(acc[q * 4], acc[q * 4 + 1], acc[q * 4 + 2], acc[q * 4 + 3]);
}

// ---------------------------------------------------------------------------
// reduce PART[b][p][jm] over p (256) + squash.
// ---------------------------------------------------------------------------
__global__ __launch_bounds__(1024)
void reduce_squash(const float* __restrict__ part, float* __restrict__ v)
{
    __shared__ float red[4][256];
    const int tid = threadIdx.x;
    const int seg = tid >> 8;
    const int loc = tid & 255;
    const int b   = blockIdx.x >> 3;
    const int jmb = (blockIdx.x & 7) * 256;

    const float* p = part + ((size_t)b * NCH + seg * 64) * JM + jmb + loc;
    float s0 = 0.f, s1 = 0.f, s2 = 0.f, s3 = 0.f;
#pragma unroll 4
    for (int q = 0; q < 64; q += 4) {
        s0 += p[(size_t)(q + 0) * JM];
        s1 += p[(size_t)(q + 1) * JM];
        s2 += p[(size_t)(q + 2) * JM];
        s3 += p[(size_t)(q + 3) * JM];
    }
    red[seg][loc] = (s0 + s1) + (s2 + s3);
    __syncthreads();

    if (tid < 256) {
        const float s = (red[0][loc] + red[1][loc]) + (red[2][loc] + red[3][loc]);
        float sq = s * s;
#pragma unroll
        for (int k = 1; k < 32; k <<= 1) sq += __shfl_xor(sq, k);
        v[(size_t)b * JM + jmb + loc] =
            (sq / (1.0f + sq)) * (s * rsqrtf(sq + 1e-7f));
    }
}

__global__ __launch_bounds__(256)
void squash_kernel(const float* __restrict__ s, float* __restrict__ v)
{
    const int g = blockIdx.x * 256 + threadIdx.x;
    const float val = s[g];
    float sq = val * val;
#pragma unroll
    for (int k = 1; k < 32; k <<= 1) sq += __shfl_xor(sq, k);
    v[g] = (sq / (1.0f + sq)) * (val * rsqrtf(sq + 1e-7f));
}

// ---------------------------------------------------------------------------
extern "C" void kernel_launch(void* const* d_in, const int* in_sizes, int n_in,
                              void* d_out, int out_size, void* d_ws, size_t ws_size,
                              hipStream_t stream)
{
    const float* x = (const float*)d_in[0];
    const float* w = (const float*)d_in[1];
    float* out = (float*)d_out;
    float* ws  = (float*)d_ws;

    float* A0   = ws;                                   // 2,097,152 f (fallback only)
    float* V0   = A0 + (size_t)B_ * CI * CJ;            // 32768 f
    float* V1   = V0 + (size_t)B_ * JM;                 // 32768 f
    float* PART = V1 + (size_t)B_ * JM;                 // 8,388,608 f
    __half* U16 = (__half*)(PART + (size_t)B_ * NCH * JM);  // 134 MB fp16

    const size_t need_part =
        ((size_t)B_ * CI * CJ + 2 * (size_t)B_ * JM
         + (size_t)B_ * NCH * JM) * sizeof(float);      // ~42.6 MB
    const size_t need_full =
        need_part + (size_t)B_ * CI * JM * sizeof(__half);  // ~176.5 MB

    if (ws_size >= need_full) {
        pass0_full<<<256, 1024, 0, stream>>>(x, w, PART, U16);
        reduce_squash<<<128, 1024, 0, stream>>>(PART, V0);
        route_kernel<false><<<1024, 256, 0, stream>>>(U16, V0, nullptr, PART);
        reduce_squash<<<128, 1024, 0, stream>>>(PART, V1);
        route_kernel<true><<<1024, 256, 0, stream>>>(U16, V0, V1, PART);
        reduce_squash<<<128, 1024, 0, stream>>>(PART, out);
    } else if (ws_size >= need_part) {
        pass_kernel<0, false, false><<<512, 1024, 0, stream>>>(x, w, nullptr, nullptr, PART, nullptr);
        reduce_squash<<<128, 1024, 0, stream>>>(PART, V0);
        pass_kernel<1, false, false><<<512, 1024, 0, stream>>>(x, w, V0, A0, PART, nullptr);
        reduce_squash<<<128, 1024, 0, stream>>>(PART, V1);
        pass_kernel<2, false, false><<<512, 1024, 0, stream>>>(x, w, V1, A0, PART, nullptr);
        reduce_squash<<<128, 1024, 0, stream>>>(PART, out);
    } else {
        float* S0 = V1 + (size_t)B_ * JM;
        float* S1 = S0 + (size_t)B_ * JM;
        float* S2 = S1 + (size_t)B_ * JM;
        hipMemsetAsync(S0, 0, (size_t)3 * B_ * JM * sizeof(float), stream);
        pass_kernel<0, true, false><<<512, 1024, 0, stream>>>(x, w, nullptr, nullptr, S0, nullptr);
        squash_kernel<<<128, 256, 0, stream>>>(S0, V0);
        pass_kernel<1, true, false><<<512, 1024, 0, stream>>>(x, w, V0, A0, S1, nullptr);
        squash_kernel<<<128, 256, 0, stream>>>(S1, V1);
        pass_kernel<2, true, false><<<512, 1024, 0, stream>>>(x, w, V1, A0, S2, nullptr);
        squash_kernel<<<128, 256, 0, stream>>>(S2, out);
    }
}

// Round 2
// 524.136 us; speedup vs baseline: 1.1164x; 1.0446x over previous
//
#include <hip/hip_runtime.h>
#include <hip/hip_fp16.h>
#include <math.h>

#define B_   16
#define CI   2048
#define NI   16
#define CJ   64
#define NJ   32
#define JM   2048      // CJ*NJ
#define CH   8         // i's per block
#define NCH  256       // i-chunks = CI/CH
#define WHALF 1024     // jm per staged half-row of w
#define ALPHA 8.0f

// ---------------------------------------------------------------------------
// R6 pass-0: w staged to LDS via global_load_lds (zero-VGPR staging -> deep
// vmcnt concurrency breaks the ~3.1 TB/s latency pin of the VGPR-transit
// path). 256 blocks x 1024 thr, 1 block/CU, LDS = 2 x 64KB wbuf + 8KB xs.
// 16 phases (8 i x 2 jm-halves): issue next-half stage -> s_waitcnt vmcnt(4)
// (counted, never 0 mid-loop) -> raw s_barrier -> compute from LDS.
// Thread = (bh 0..3) x (jg 0..255): 4 b's x 4 jm per half (8 jm total).
// acc indexed by LITERAL h (rule: no runtime-indexed register arrays).
// ---------------------------------------------------------------------------
__global__ __launch_bounds__(1024)
void pass0_full(const float* __restrict__ x, const float* __restrict__ w,
                float* __restrict__ part, __half* __restrict__ U16)
{
    __shared__ float wlds[2][NI][WHALF];   // 2 x 64 KB
    __shared__ float xs[CH][16][NI];       // 8 KB

    const int ichunk = blockIdx.x;
    const int i0     = ichunk * CH;
    const int tid    = threadIdx.x;
    const int bh     = tid >> 8;           // 0..3
    const int jg     = tid & 255;          // jm-group (4 consecutive jm)
    const int wv_    = tid >> 6;           // wave 0..15
    const int lane   = tid & 63;
    const int fi_base = wv_ * 256 + lane * 4;   // flat float idx in 16K-float half

    // stage x (512 threads x 4 floats = 8 KB)
    if (tid < 512) {
        const int f  = tid * 4;
        const int n  = f & 15;
        const int b  = (f >> 4) & 15;
        const int ci = f >> 8;
        *(float4*)(&xs[ci][b][n]) =
            *(const float4*)(x + ((size_t)b * CI + (i0 + ci)) * NI + n);
    }

    float acc[4][2][4];
#pragma unroll
    for (int bb = 0; bb < 4; ++bb)
#pragma unroll
        for (int h = 0; h < 2; ++h)
#pragma unroll
            for (int k = 0; k < 4; ++k) acc[bb][h][k] = 0.0f;

    float* const wbase = &wlds[0][0][0];

    // stage one 64KB half (16n x 1024jm) of w[i] into buffer dstbuf.
    // Per wave: 4 x global_load_lds(16B); LDS dest = uniform base + lane*16.
    auto stage = [&](int ci_, int h_, int dstbuf) {
        const float* gb = w + (size_t)(i0 + ci_) * (NI * JM) + h_ * WHALF;
#pragma unroll
        for (int q = 0; q < 4; ++q) {
            const int fi = fi_base + q * 4096;
            const int n_ = fi >> 10;
            const int c_ = fi & 1023;
            const float* g = gb + n_ * JM + c_;
            float* lb = wbase + (dstbuf * (NI * WHALF) + wv_ * 256 + q * 4096);
            __builtin_amdgcn_global_load_lds(
                (const __attribute__((address_space(1))) void*)g,
                (__attribute__((address_space(3))) void*)lb, 16, 0, 0);
        }
    };

    __syncthreads();          // xs visible (full drain; nothing else in flight)

    int buf = 0;
    stage(0, 0, 0);           // prologue: (ci=0, h=0) -> buf 0

    for (int ci = 0; ci < CH; ++ci) {
        const int i = i0 + ci;

        // ---- one phase, h is a LITERAL ----
#define PHASE(H, NEXT_CI, NEXT_H, IS_LAST)                                     \
        do {                                                                   \
            if (!(IS_LAST)) {                                                  \
                stage((NEXT_CI), (NEXT_H), buf ^ 1);                           \
                asm volatile("s_waitcnt vmcnt(4)" ::: "memory");               \
            } else {                                                           \
                asm volatile("s_waitcnt vmcnt(0)" ::: "memory");               \
            }                                                                  \
            __builtin_amdgcn_s_barrier();                                      \
            __builtin_amdgcn_sched_barrier(0);                                 \
            float uu[4][4];                                                    \
            _Pragma("unroll")                                                  \
            for (int bb = 0; bb < 4; ++bb)                                     \
                _Pragma("unroll")                                              \
                for (int k = 0; k < 4; ++k) uu[bb][k] = 0.0f;                  \
            const float* wb = wbase + buf * (NI * WHALF);                      \
            _Pragma("unroll")                                                  \
            for (int n = 0; n < NI; ++n) {                                     \
                const float4 wq = *(const float4*)(wb + n * WHALF + jg * 4);   \
                _Pragma("unroll")                                              \
                for (int bb = 0; bb < 4; ++bb) {                               \
                    const float xv = xs[ci][bh * 4 + bb][n];                   \
                    uu[bb][0] = fmaf(xv, wq.x, uu[bb][0]);                     \
                    uu[bb][1] = fmaf(xv, wq.y, uu[bb][1]);                     \
                    uu[bb][2] = fmaf(xv, wq.z, uu[bb][2]);                     \
                    uu[bb][3] = fmaf(xv, wq.w, uu[bb][3]);                     \
                }                                                              \
            }                                                                  \
            _Pragma("unroll")                                                  \
            for (int bb = 0; bb < 4; ++bb) {                                   \
                const int b = bh * 4 + bb;                                     \
                _Pragma("unroll")                                              \
                for (int k = 0; k < 4; ++k)                                    \
                    acc[bb][H][k] += uu[bb][k];                                \
                union { uint2 d; __half hh[4]; } pk;                           \
                _Pragma("unroll")                                              \
                for (int k = 0; k < 4; ++k) pk.hh[k] = __float2half(uu[bb][k]);\
                *(uint2*)(U16 + ((size_t)b * CI + i) * JM                      \
                          + (H) * WHALF + jg * 4) = pk.d;                      \
            }                                                                  \
            __builtin_amdgcn_s_barrier();                                      \
            buf ^= 1;                                                          \
        } while (0)

        PHASE(0, ci, 1, false);
        PHASE(1, ci + 1, 0, ci == CH - 1);
#undef PHASE
    }

#pragma unroll
    for (int bb = 0; bb < 4; ++bb) {
        const int b = bh * 4 + bb;
        float* dst = part + ((size_t)b * NCH + ichunk) * JM + jg * 4;
        *(float4*)(dst) =
            make_float4(acc[bb][0][0], acc[bb][0][1], acc[bb][0][2], acc[bb][0][3]);
        *(float4*)(dst + WHALF) =
            make_float4(acc[bb][1][0], acc[bb][1][1], acc[bb][1][2], acc[bb][1][3]);
    }
}

// ---------------------------------------------------------------------------
// Legacy pass kernel (fallback paths only).
// ---------------------------------------------------------------------------
template <int PASS, bool ATOMIC, bool STOREU>
__global__ __launch_bounds__(1024)
void pass_kernel(const float* __restrict__ x, const float* __restrict__ w,
                 const float* __restrict__ vprev, float* __restrict__ a0,
                 float* __restrict__ sout, __half* __restrict__ U16)
{
    __shared__ float xs[CH][8][NI];
    __shared__ float Ls[8][CJ];
    __shared__ float smax[8], sinv[8];

    const int idx    = blockIdx.x;
    const int xcd    = idx & 7;
    const int bhalf  = (idx >> 3) & 1;
    const int slot   = idx >> 4;
    const int ichunk = slot * 8 + xcd;
    const int i0     = ichunk * CH;
    const int b0     = bhalf * 8;

    const int tid  = threadIdx.x;
    const int bh   = tid >> 8;
    const int jg   = tid & 255;
    const int jm0  = jg * 8;
    const int jcol = jg >> 2;

    if (tid < 256) {
        const int f  = tid * 4;
        const int n  = f & 15;
        const int bg = (f >> 4) & 7;
        const int ci = f >> 7;
        *(float4*)(&xs[ci][bg][n]) =
            *(const float4*)(x + ((size_t)(b0 + bg) * CI + (i0 + ci)) * NI + n);
    }

    float acc[2][8];
#pragma unroll
    for (int bb = 0; bb < 2; ++bb)
#pragma unroll
        for (int k = 0; k < 8; ++k) acc[bb][k] = 0.0f;

    __syncthreads();

    for (int ci = 0; ci < CH; ++ci) {
        const int i = i0 + ci;

        float u[2][8];
#pragma unroll
        for (int bb = 0; bb < 2; ++bb)
#pragma unroll
            for (int k = 0; k < 8; ++k) u[bb][k] = 0.0f;

        const float* wrow = w + (size_t)i * (NI * JM) + jm0;
#pragma unroll
        for (int n = 0; n < NI; ++n) {
            const float4 w0 = *(const float4*)(wrow + (size_t)n * JM);
            const float4 w1 = *(const float4*)(wrow + (size_t)n * JM + 4);
#pragma unroll
            for (int bb = 0; bb < 2; ++bb) {
                const float xv = xs[ci][bh * 2 + bb][n];
                u[bb][0] = fmaf(xv, w0.x, u[bb][0]);
                u[bb][1] = fmaf(xv, w0.y, u[bb][1]);
                u[bb][2] = fmaf(xv, w0.z, u[bb][2]);
                u[bb][3] = fmaf(xv, w0.w, u[bb][3]);
                u[bb][4] = fmaf(xv, w1.x, u[bb][4]);
                u[bb][5] = fmaf(xv, w1.y, u[bb][5]);
                u[bb][6] = fmaf(xv, w1.z, u[bb][6]);
                u[bb][7] = fmaf(xv, w1.w, u[bb][7]);
            }
        }

        if (PASS == 0) {
#pragma unroll
            for (int bb = 0; bb < 2; ++bb)
#pragma unroll
                for (int k = 0; k < 8; ++k) acc[bb][k] += u[bb][k];
            if (STOREU) {
#pragma unroll
                for (int bb = 0; bb < 2; ++bb) {
                    const int b = b0 + bh * 2 + bb;
                    union { uint4 q; __half h[8]; } pk;
#pragma unroll
                    for (int k = 0; k < 8; ++k) pk.h[k] = __float2half(u[bb][k]);
                    *(uint4*)(U16 + ((size_t)b * CI + i) * JM + jm0) = pk.q;
                }
            }
        } else {
            float ap[2];
#pragma unroll
            for (int bb = 0; bb < 2; ++bb) {
                const int b = b0 + bh * 2 + bb;
                const float4 v0 = *(const float4*)(vprev + (size_t)b * JM + jm0);
                const float4 v1 = *(const float4*)(vprev + (size_t)b * JM + jm0 + 4);
                float t = u[bb][0] * v0.x + u[bb][1] * v0.y
                        + u[bb][2] * v0.z + u[bb][3] * v0.w
                        + u[bb][4] * v1.x + u[bb][5] * v1.y
                        + u[bb][6] * v1.z + u[bb][7] * v1.w;
                t += __shfl_xor(t, 1);
                t += __shfl_xor(t, 2);
                ap[bb] = t;
            }

            float L[2];
#pragma unroll
            for (int bb = 0; bb < 2; ++bb) {
                if (PASS == 1) {
                    L[bb] = ap[bb];
                } else {
                    const int b = b0 + bh * 2 + bb;
                    L[bb] = ap[bb] + a0[((size_t)b * CI + i) * CJ + jcol];
                }
            }
            if ((jg & 3) == 0) {
#pragma unroll
                for (int bb = 0; bb < 2; ++bb) {
                    const int bg = bh * 2 + bb;
                    Ls[bg][jcol] = L[bb];
                    if (PASS == 1)
                        a0[((size_t)(b0 + bg) * CI + i) * CJ + jcol] = ap[bb];
                }
            }
            __syncthreads();

            if (tid < 256) {
                const int rb = tid >> 5, rj = tid & 31;
                const float x1 = Ls[rb][rj];
                const float x2 = Ls[rb][rj + 32];
                float mx = fmaxf(x1, x2);
#pragma unroll
                for (int s2 = 1; s2 < 32; s2 <<= 1)
                    mx = fmaxf(mx, __shfl_xor(mx, s2));
                float ex = __expf(ALPHA * (x1 - mx)) + __expf(ALPHA * (x2 - mx));
#pragma unroll
                for (int s2 = 1; s2 < 32; s2 <<= 1)
                    ex += __shfl_xor(ex, s2);
                if (rj == 0) { smax[rb] = mx; sinv[rb] = 64.0f / ex; }
            }
            __syncthreads();

#pragma unroll
            for (int bb = 0; bb < 2; ++bb) {
                const int bg = bh * 2 + bb;
                const float c = __expf(ALPHA * (L[bb] - smax[bg])) * sinv[bg];
#pragma unroll
                for (int k = 0; k < 8; ++k)
                    acc[bb][k] = fmaf(c, u[bb][k], acc[bb][k]);
            }
        }
    }

    if (ATOMIC) {
#pragma unroll
        for (int bb = 0; bb < 2; ++bb) {
            const int b = b0 + bh * 2 + bb;
#pragma unroll
            for (int k = 0; k < 8; ++k)
                unsafeAtomicAdd(sout + (size_t)b * JM + jm0 + k, acc[bb][k]);
        }
    } else {
#pragma unroll
        for (int bb = 0; bb < 2; ++bb) {
            const int b = b0 + bh * 2 + bb;
            float* dst = sout + ((size_t)b * NCH + ichunk) * JM + jm0;
            *(float4*)(dst)     =
                make_float4(acc[bb][0], acc[bb][1], acc[bb][2], acc[bb][3]);
            *(float4*)(dst + 4) =
                make_float4(acc[bb][4], acc[bb][5], acc[bb][6], acc[bb][7]);
        }
    }
}

// ---------------------------------------------------------------------------
// R6 routing pass. Register-resident v (vr[32]); fp16 u rows prefetched
// distance-2. Softmax WITHOUT max-subtraction: |8L| <= ~40 (||v||<1 by
// squash, ||u||~1-3) so e^(8L) is f32-safe and ratios are exact-math
// identical -> halves the shfl chain (6 instead of 12) and drops the
// dependent max->exp. ap computed as 4 partial chains (depth 8, not 64).
// PASS2 folds (v0+v1) into vr (TWO=true): no a0 traffic at all.
// grid: 1024 blocks = b(16) x ig(64); 256 thr = 4 waves x 8 i.
// ---------------------------------------------------------------------------
template <bool TWO>
__global__ __launch_bounds__(256)
void route_kernel(const __half* __restrict__ U16, const float* __restrict__ va,
                  const float* __restrict__ vb, float* __restrict__ part)
{
    const int tid = threadIdx.x;
    const int b   = blockIdx.x >> 6;
    const int ig  = blockIdx.x & 63;
    const int wv  = tid >> 6;
    const int l   = tid & 63;       // j = l

    float vr[32];
#pragma unroll
    for (int q = 0; q < 8; ++q) {
        const float4 f = *(const float4*)(va + (size_t)b * JM + l * 32 + q * 4);
        vr[q * 4 + 0] = f.x; vr[q * 4 + 1] = f.y;
        vr[q * 4 + 2] = f.z; vr[q * 4 + 3] = f.w;
    }
    if (TWO) {
#pragma unroll
        for (int q = 0; q < 8; ++q) {
            const float4 f = *(const float4*)(vb + (size_t)b * JM + l * 32 + q * 4);
            vr[q * 4 + 0] += f.x; vr[q * 4 + 1] += f.y;
            vr[q * 4 + 2] += f.z; vr[q * 4 + 3] += f.w;
        }
    }

    float acc[32];
#pragma unroll
    for (int m = 0; m < 32; ++m) acc[m] = 0.0f;

    const __half* up0 = U16 + ((size_t)b * CI + ig * 32 + wv * 8) * JM + l * 32;

    union F4H { float4 f; __half2 h2[4]; };
    F4H buf[2][4];
#pragma unroll
    for (int r = 0; r < 2; ++r)
#pragma unroll
        for (int q = 0; q < 4; ++q)
            buf[r][q].f = *(const float4*)(up0 + (size_t)r * JM + q * 8);

#pragma unroll
    for (int ii = 0; ii < 8; ++ii) {
        F4H cu[4];
#pragma unroll
        for (int q = 0; q < 4; ++q) cu[q] = buf[ii & 1][q];

        if (ii + 2 < 8) {
#pragma unroll
            for (int q = 0; q < 4; ++q)
                buf[ii & 1][q].f = *(const float4*)(up0 + (size_t)(ii + 2) * JM + q * 8);
        }

        // ap = sum_m vr[m]*u[m], 4 independent partial chains (depth 8)
        float p0 = 0.f, p1 = 0.f, p2 = 0.f, p3 = 0.f;
#pragma unroll
        for (int p = 0; p < 4; ++p) {
            const float2 u0 = __half22float2(cu[0].h2[p]);
            const float2 u1 = __half22float2(cu[1].h2[p]);
            const float2 u2 = __half22float2(cu[2].h2[p]);
            const float2 u3 = __half22float2(cu[3].h2[p]);
            p0 = fmaf(vr[p * 2],      u0.x, p0); p0 = fmaf(vr[p * 2 + 1],  u0.y, p0);
            p1 = fmaf(vr[8 + p * 2],  u1.x, p1); p1 = fmaf(vr[9 + p * 2],  u1.y, p1);
            p2 = fmaf(vr[16 + p * 2], u2.x, p2); p2 = fmaf(vr[17 + p * 2], u2.y, p2);
            p3 = fmaf(vr[24 + p * 2], u3.x, p3); p3 = fmaf(vr[25 + p * 2], u3.y, p3);
        }
        const float ap = (p0 + p1) + (p2 + p3);

        // softmax over 64 j, no max-subtraction (range-safe, see header)
        const float e = __expf(ALPHA * ap);
        float se = e;
#pragma unroll
        for (int d = 1; d < 64; d <<= 1)
            se += __shfl_xor(se, d);
        const float c = e * (64.0f / se);

#pragma unroll
        for (int q = 0; q < 4; ++q)
#pragma unroll
            for (int p = 0; p < 4; ++p) {
                const float2 uf = __half22float2(cu[q].h2[p]);
                const int m = q * 8 + p * 2;
                acc[m]     = fmaf(c, uf.x, acc[m]);
                acc[m + 1] = fmaf(c, uf.y, acc[m + 1]);
            }
    }

    float* dst = part + ((size_t)b * NCH + (ig * 4 + wv)) * JM + l * 32;
#pragma unroll
    for (int q = 0; q < 8; ++q)
        *(float4*)(dst + q * 4) =
            make_float4(acc[q * 4], acc[q * 4 + 1], acc[q * 4 + 2], acc[q * 4 + 3]);
}

// ---------------------------------------------------------------------------
// reduce PART[b][p][jm] over p (256) + squash.
// ---------------------------------------------------------------------------
__global__ __launch_bounds__(1024)
void reduce_squash(const float* __restrict__ part, float* __restrict__ v)
{
    __shared__ float red[4][256];
    const int tid = threadIdx.x;
    const int seg = tid >> 8;
    const int loc = tid & 255;
    const int b   = blockIdx.x >> 3;
    const int jmb = (blockIdx.x & 7) * 256;

    const float* p = part + ((size_t)b * NCH + seg * 64) * JM + jmb + loc;
    float s0 = 0.f, s1 = 0.f, s2 = 0.f, s3 = 0.f;
#pragma unroll 4
    for (int q = 0; q < 64; q += 4) {
        s0 += p[(size_t)(q + 0) * JM];
        s1 += p[(size_t)(q + 1) * JM];
        s2 += p[(size_t)(q + 2) * JM];
        s3 += p[(size_t)(q + 3) * JM];
    }
    red[seg][loc] = (s0 + s1) + (s2 + s3);
    __syncthreads();

    if (tid < 256) {
        const float s = (red[0][loc] + red[1][loc]) + (red[2][loc] + red[3][loc]);
        float sq = s * s;
#pragma unroll
        for (int k = 1; k < 32; k <<= 1) sq += __shfl_xor(sq, k);
        v[(size_t)b * JM + jmb + loc] =
            (sq / (1.0f + sq)) * (s * rsqrtf(sq + 1e-7f));
    }
}

__global__ __launch_bounds__(256)
void squash_kernel(const float* __restrict__ s, float* __restrict__ v)
{
    const int g = blockIdx.x * 256 + threadIdx.x;
    const float val = s[g];
    float sq = val * val;
#pragma unroll
    for (int k = 1; k < 32; k <<= 1) sq += __shfl_xor(sq, k);
    v[g] = (sq / (1.0f + sq)) * (val * rsqrtf(sq + 1e-7f));
}

// ---------------------------------------------------------------------------
extern "C" void kernel_launch(void* const* d_in, const int* in_sizes, int n_in,
                              void* d_out, int out_size, void* d_ws, size_t ws_size,
                              hipStream_t stream)
{
    const float* x = (const float*)d_in[0];
    const float* w = (const float*)d_in[1];
    float* out = (float*)d_out;
    float* ws  = (float*)d_ws;

    float* A0   = ws;                                   // fallback only
    float* V0   = A0 + (size_t)B_ * CI * CJ;
    float* V1   = V0 + (size_t)B_ * JM;
    float* PART = V1 + (size_t)B_ * JM;
    __half* U16 = (__half*)(PART + (size_t)B_ * NCH * JM);

    const size_t need_part =
        ((size_t)B_ * CI * CJ + 2 * (size_t)B_ * JM
         + (size_t)B_ * NCH * JM) * sizeof(float);
    const size_t need_full =
        need_part + (size_t)B_ * CI * JM * sizeof(__half);

    if (ws_size >= need_full) {
        pass0_full<<<256, 1024, 0, stream>>>(x, w, PART, U16);
        reduce_squash<<<128, 1024, 0, stream>>>(PART, V0);
        route_kernel<false><<<1024, 256, 0, stream>>>(U16, V0, nullptr, PART);
        reduce_squash<<<128, 1024, 0, stream>>>(PART, V1);
        route_kernel<true><<<1024, 256, 0, stream>>>(U16, V0, V1, PART);
        reduce_squash<<<128, 1024, 0, stream>>>(PART, out);
    } else if (ws_size >= need_part) {
        pass_kernel<0, false, false><<<512, 1024, 0, stream>>>(x, w, nullptr, nullptr, PART, nullptr);
        reduce_squash<<<128, 1024, 0, stream>>>(PART, V0);
        pass_kernel<1, false, false><<<512, 1024, 0, stream>>>(x, w, V0, A0, PART, nullptr);
        reduce_squash<<<128, 1024, 0, stream>>>(PART, V1);
        pass_kernel<2, false, false><<<512, 1024, 0, stream>>>(x, w, V1, A0, PART, nullptr);
        reduce_squash<<<128, 1024, 0, stream>>>(PART, out);
    } else {
        float* S0 = V1 + (size_t)B_ * JM;
        float* S1 = S0 + (size_t)B_ * JM;
        float* S2 = S1 + (size_t)B_ * JM;
        hipMemsetAsync(S0, 0, (size_t)3 * B_ * JM * sizeof(float), stream);
        pass_kernel<0, true, false><<<512, 1024, 0, stream>>>(x, w, nullptr, nullptr, S0, nullptr);
        squash_kernel<<<128, 256, 0, stream>>>(S0, V0);
        pass_kernel<1, true, false><<<512, 1024, 0, stream>>>(x, w, V0, A0, S1, nullptr);
        squash_kernel<<<128, 256, 0, stream>>>(S1, V1);
        pass_kernel<2, true, false><<<512, 1024, 0, stream>>>(x, w, V1, A0, S2, nullptr);
        squash_kernel<<<128, 256, 0, stream>>>(S2, out);
    }
}

// Round 3
// 498.697 us; speedup vs baseline: 1.1733x; 1.0510x over previous
//
#include <hip/hip_runtime.h>
#include <hip/hip_fp16.h>
#include <math.h>

#define B_   16
#define CI   2048
#define NI   16
#define CJ   64
#define NJ   32
#define JM   2048      // CJ*NJ
#define CH   8         // i's per block
#define NCH  256       // i-chunks = CI/CH
#define QW   512       // jm per staged quarter of w row
#define ALPHA 8.0f

// ---------------------------------------------------------------------------
// R7 pass-0: quarter-tile (32KB) 4-buffer depth-3 pipeline via global_load_lds
// with slc/nt (aux=2) streaming hint on the once-read w.
// 256 blocks x 1024 thr (1 block/CU), LDS = 4 x 32KB wbuf + 8KB xs = 136KB.
// 32 phases (8 ci x 4 quarters). Per phase per wave: 2 global_load_lds(16B)
// staging quarter gp+3 -> counted s_waitcnt vmcnt(6) (U16 stores also count
// in vmcnt; by issue order the youngest 6 = 2 loads(gp+3) + 4 stores(gp-1),
// so vmcnt(6) guarantees loads(gp) complete without draining the prefetch
// of gp+3) -> raw s_barrier -> compute from LDS -> s_barrier.
// Buffer reuse distance 4 > depth 3: no WAR hazard across the end barrier.
// acc/uu indexed by LITERAL Q only (no runtime-indexed register arrays).
// ---------------------------------------------------------------------------
__global__ __launch_bounds__(1024)
void pass0_full(const float* __restrict__ x, const float* __restrict__ w,
                float* __restrict__ part, __half* __restrict__ U16)
{
    __shared__ float wlds[4][NI][QW];   // 128 KB
    __shared__ float xs[CH][16][NI];    // 8 KB

    const int ichunk = blockIdx.x;
    const int i0     = ichunk * CH;
    const int tid    = threadIdx.x;
    const int bh     = tid >> 8;        // 0..3
    const int jg     = tid & 255;       // 2 jm per quarter
    const int wv_    = tid >> 6;        // wave 0..15  (stages w row n = wv_)
    const int lane   = tid & 63;

    if (tid < 512) {
        const int f  = tid * 4;
        const int n  = f & 15;
        const int b  = (f >> 4) & 15;
        const int ci = f >> 8;
        *(float4*)(&xs[ci][b][n]) =
            *(const float4*)(x + ((size_t)b * CI + (i0 + ci)) * NI + n);
    }

    float acc[4][4][2];                 // [bb][Q][k]
#pragma unroll
    for (int bb = 0; bb < 4; ++bb)
#pragma unroll
        for (int q = 0; q < 4; ++q) {
            acc[bb][q][0] = 0.0f; acc[bb][q][1] = 0.0f;
        }

    float* const wbase = &wlds[0][0][0];

    // stage one 32KB quarter (16n x 512jm) of w[i0+ci_] into buffer bufq.
    // wave wv_ stages row n=wv_: 2 x global_load_lds(16B), aux=2 (slc/nt).
    auto stage = [&](int ci_, int q_, int bufq) {
        const float* gb = w + ((size_t)(i0 + ci_) * NI + wv_) * JM
                            + q_ * QW + lane * 4;
        float* lb = wbase + bufq * (NI * QW) + wv_ * QW;
        __builtin_amdgcn_global_load_lds(
            (const __attribute__((address_space(1))) void*)gb,
            (__attribute__((address_space(3))) void*)lb, 16, 0, 2);
        __builtin_amdgcn_global_load_lds(
            (const __attribute__((address_space(1))) void*)(gb + 256),
            (__attribute__((address_space(3))) void*)(lb + 256), 16, 0, 2);
    };

    __syncthreads();                    // xs visible

    stage(0, 0, 0); stage(0, 1, 1); stage(0, 2, 2);   // prologue: gp 0,1,2

#define QP(Q, CI_, DOSTAGE, VMC)                                               \
    do {                                                                       \
        if (DOSTAGE)                                                           \
            stage((CI_) + (((Q) + 3) >> 2), ((Q) + 3) & 3, ((Q) + 3) & 3);     \
        asm volatile("s_waitcnt vmcnt(" #VMC ")" ::: "memory");                \
        __builtin_amdgcn_s_barrier();                                          \
        __builtin_amdgcn_sched_barrier(0);                                     \
        float uu[4][2];                                                        \
        _Pragma("unroll")                                                      \
        for (int bb = 0; bb < 4; ++bb) { uu[bb][0] = 0.f; uu[bb][1] = 0.f; }   \
        const float* wb = wbase + (Q) * (NI * QW);                             \
        _Pragma("unroll")                                                      \
        for (int n = 0; n < NI; ++n) {                                         \
            const float2 w2 = *(const float2*)(wb + n * QW + jg * 2);          \
            _Pragma("unroll")                                                  \
            for (int bb = 0; bb < 4; ++bb) {                                   \
                const float xv = xs[CI_][bh * 4 + bb][n];                      \
                uu[bb][0] = fmaf(xv, w2.x, uu[bb][0]);                         \
                uu[bb][1] = fmaf(xv, w2.y, uu[bb][1]);                         \
            }                                                                  \
        }                                                                      \
        _Pragma("unroll")                                                      \
        for (int bb = 0; bb < 4; ++bb) {                                       \
            const int b = bh * 4 + bb;                                         \
            acc[bb][Q][0] += uu[bb][0];                                        \
            acc[bb][Q][1] += uu[bb][1];                                        \
            union { unsigned int u32; __half h[2]; } pk;                       \
            pk.h[0] = __float2half(uu[bb][0]);                                 \
            pk.h[1] = __float2half(uu[bb][1]);                                 \
            *(unsigned int*)(U16 + ((size_t)b * CI + (i0 + (CI_))) * JM        \
                             + (Q) * QW + jg * 2) = pk.u32;                    \
        }                                                                      \
        __builtin_amdgcn_s_barrier();                                          \
    } while (0)

    for (int ci = 0; ci < 7; ++ci) {
        QP(0, ci, true, 6);
        QP(1, ci, true, 6);
        QP(2, ci, true, 6);
        QP(3, ci, true, 6);
    }
    {
        const int ci = 7;
        QP(0, ci, true, 6);     // stages gp=31 (last)
        QP(1, ci, false, 4);
        QP(2, ci, false, 2);
        QP(3, ci, false, 0);
    }
#undef QP

#pragma unroll
    for (int bb = 0; bb < 4; ++bb) {
        const int b = bh * 4 + bb;
        float* dst = part + ((size_t)b * NCH + ichunk) * JM + jg * 2;
        *(float2*)(dst)            = make_float2(acc[bb][0][0], acc[bb][0][1]);
        *(float2*)(dst + QW)       = make_float2(acc[bb][1][0], acc[bb][1][1]);
        *(float2*)(dst + 2 * QW)   = make_float2(acc[bb][2][0], acc[bb][2][1]);
        *(float2*)(dst + 3 * QW)   = make_float2(acc[bb][3][0], acc[bb][3][1]);
    }
}

// ---------------------------------------------------------------------------
// Legacy pass kernel (fallback paths only).
// ---------------------------------------------------------------------------
template <int PASS, bool ATOMIC, bool STOREU>
__global__ __launch_bounds__(1024)
void pass_kernel(const float* __restrict__ x, const float* __restrict__ w,
                 const float* __restrict__ vprev, float* __restrict__ a0,
                 float* __restrict__ sout, __half* __restrict__ U16)
{
    __shared__ float xs[CH][8][NI];
    __shared__ float Ls[8][CJ];
    __shared__ float smax[8], sinv[8];

    const int idx    = blockIdx.x;
    const int xcd    = idx & 7;
    const int bhalf  = (idx >> 3) & 1;
    const int slot   = idx >> 4;
    const int ichunk = slot * 8 + xcd;
    const int i0     = ichunk * CH;
    const int b0     = bhalf * 8;

    const int tid  = threadIdx.x;
    const int bh   = tid >> 8;
    const int jg   = tid & 255;
    const int jm0  = jg * 8;
    const int jcol = jg >> 2;

    if (tid < 256) {
        const int f  = tid * 4;
        const int n  = f & 15;
        const int bg = (f >> 4) & 7;
        const int ci = f >> 7;
        *(float4*)(&xs[ci][bg][n]) =
            *(const float4*)(x + ((size_t)(b0 + bg) * CI + (i0 + ci)) * NI + n);
    }

    float acc[2][8];
#pragma unroll
    for (int bb = 0; bb < 2; ++bb)
#pragma unroll
        for (int k = 0; k < 8; ++k) acc[bb][k] = 0.0f;

    __syncthreads();

    for (int ci = 0; ci < CH; ++ci) {
        const int i = i0 + ci;

        float u[2][8];
#pragma unroll
        for (int bb = 0; bb < 2; ++bb)
#pragma unroll
            for (int k = 0; k < 8; ++k) u[bb][k] = 0.0f;

        const float* wrow = w + (size_t)i * (NI * JM) + jm0;
#pragma unroll
        for (int n = 0; n < NI; ++n) {
            const float4 w0 = *(const float4*)(wrow + (size_t)n * JM);
            const float4 w1 = *(const float4*)(wrow + (size_t)n * JM + 4);
#pragma unroll
            for (int bb = 0; bb < 2; ++bb) {
                const float xv = xs[ci][bh * 2 + bb][n];
                u[bb][0] = fmaf(xv, w0.x, u[bb][0]);
                u[bb][1] = fmaf(xv, w0.y, u[bb][1]);
                u[bb][2] = fmaf(xv, w0.z, u[bb][2]);
                u[bb][3] = fmaf(xv, w0.w, u[bb][3]);
                u[bb][4] = fmaf(xv, w1.x, u[bb][4]);
                u[bb][5] = fmaf(xv, w1.y, u[bb][5]);
                u[bb][6] = fmaf(xv, w1.z, u[bb][6]);
                u[bb][7] = fmaf(xv, w1.w, u[bb][7]);
            }
        }

        if (PASS == 0) {
#pragma unroll
            for (int bb = 0; bb < 2; ++bb)
#pragma unroll
                for (int k = 0; k < 8; ++k) acc[bb][k] += u[bb][k];
            if (STOREU) {
#pragma unroll
                for (int bb = 0; bb < 2; ++bb) {
                    const int b = b0 + bh * 2 + bb;
                    union { uint4 q; __half h[8]; } pk;
#pragma unroll
                    for (int k = 0; k < 8; ++k) pk.h[k] = __float2half(u[bb][k]);
                    *(uint4*)(U16 + ((size_t)b * CI + i) * JM + jm0) = pk.q;
                }
            }
        } else {
            float ap[2];
#pragma unroll
            for (int bb = 0; bb < 2; ++bb) {
                const int b = b0 + bh * 2 + bb;
                const float4 v0 = *(const float4*)(vprev + (size_t)b * JM + jm0);
                const float4 v1 = *(const float4*)(vprev + (size_t)b * JM + jm0 + 4);
                float t = u[bb][0] * v0.x + u[bb][1] * v0.y
                        + u[bb][2] * v0.z + u[bb][3] * v0.w
                        + u[bb][4] * v1.x + u[bb][5] * v1.y
                        + u[bb][6] * v1.z + u[bb][7] * v1.w;
                t += __shfl_xor(t, 1);
                t += __shfl_xor(t, 2);
                ap[bb] = t;
            }

            float L[2];
#pragma unroll
            for (int bb = 0; bb < 2; ++bb) {
                if (PASS == 1) {
                    L[bb] = ap[bb];
                } else {
                    const int b = b0 + bh * 2 + bb;
                    L[bb] = ap[bb] + a0[((size_t)b * CI + i) * CJ + jcol];
                }
            }
            if ((jg & 3) == 0) {
#pragma unroll
                for (int bb = 0; bb < 2; ++bb) {
                    const int bg = bh * 2 + bb;
                    Ls[bg][jcol] = L[bb];
                    if (PASS == 1)
                        a0[((size_t)(b0 + bg) * CI + i) * CJ + jcol] = ap[bb];
                }
            }
            __syncthreads();

            if (tid < 256) {
                const int rb = tid >> 5, rj = tid & 31;
                const float x1 = Ls[rb][rj];
                const float x2 = Ls[rb][rj + 32];
                float mx = fmaxf(x1, x2);
#pragma unroll
                for (int s2 = 1; s2 < 32; s2 <<= 1)
                    mx = fmaxf(mx, __shfl_xor(mx, s2));
                float ex = __expf(ALPHA * (x1 - mx)) + __expf(ALPHA * (x2 - mx));
#pragma unroll
                for (int s2 = 1; s2 < 32; s2 <<= 1)
                    ex += __shfl_xor(ex, s2);
                if (rj == 0) { smax[rb] = mx; sinv[rb] = 64.0f / ex; }
            }
            __syncthreads();

#pragma unroll
            for (int bb = 0; bb < 2; ++bb) {
                const int bg = bh * 2 + bb;
                const float c = __expf(ALPHA * (L[bb] - smax[bg])) * sinv[bg];
#pragma unroll
                for (int k = 0; k < 8; ++k)
                    acc[bb][k] = fmaf(c, u[bb][k], acc[bb][k]);
            }
        }
    }

    if (ATOMIC) {
#pragma unroll
        for (int bb = 0; bb < 2; ++bb) {
            const int b = b0 + bh * 2 + bb;
#pragma unroll
            for (int k = 0; k < 8; ++k)
                unsafeAtomicAdd(sout + (size_t)b * JM + jm0 + k, acc[bb][k]);
        }
    } else {
#pragma unroll
        for (int bb = 0; bb < 2; ++bb) {
            const int b = b0 + bh * 2 + bb;
            float* dst = sout + ((size_t)b * NCH + ichunk) * JM + jm0;
            *(float4*)(dst)     =
                make_float4(acc[bb][0], acc[bb][1], acc[bb][2], acc[bb][3]);
            *(float4*)(dst + 4) =
                make_float4(acc[bb][4], acc[bb][5], acc[bb][6], acc[bb][7]);
        }
    }
}

// ---------------------------------------------------------------------------
// R7 routing pass. Register-resident v (vr[32]); fp16 u rows prefetched
// distance-2; no-max softmax (|8L| <= ~40, f32-safe, ratios exact); ap as
// 4 partial chains. NEW: cross-wave LDS combine -> 64 partials per b
// (PART row = ig), cutting route PART write 33.5 -> 8.4 MB and reduce
// reads likewise. grid: 1024 blocks = b(16) x ig(64); 256 thr = 4 wv x 8 i.
// ---------------------------------------------------------------------------
template <bool TWO>
__global__ __launch_bounds__(256)
void route_kernel(const __half* __restrict__ U16, const float* __restrict__ va,
                  const float* __restrict__ vb, float* __restrict__ part)
{
    __shared__ float red[4][64][33];    // +1 pad: conflict-free lane writes

    const int tid = threadIdx.x;
    const int b   = blockIdx.x >> 6;
    const int ig  = blockIdx.x & 63;
    const int wv  = tid >> 6;
    const int l   = tid & 63;       // j = l

    float vr[32];
#pragma unroll
    for (int q = 0; q < 8; ++q) {
        const float4 f = *(const float4*)(va + (size_t)b * JM + l * 32 + q * 4);
        vr[q * 4 + 0] = f.x; vr[q * 4 + 1] = f.y;
        vr[q * 4 + 2] = f.z; vr[q * 4 + 3] = f.w;
    }
    if (TWO) {
#pragma unroll
        for (int q = 0; q < 8; ++q) {
            const float4 f = *(const float4*)(vb + (size_t)b * JM + l * 32 + q * 4);
            vr[q * 4 + 0] += f.x; vr[q * 4 + 1] += f.y;
            vr[q * 4 + 2] += f.z; vr[q * 4 + 3] += f.w;
        }
    }

    float acc[32];
#pragma unroll
    for (int m = 0; m < 32; ++m) acc[m] = 0.0f;

    const __half* up0 = U16 + ((size_t)b * CI + ig * 32 + wv * 8) * JM + l * 32;

    union F4H { float4 f; __half2 h2[4]; };
    F4H buf[2][4];
#pragma unroll
    for (int r = 0; r < 2; ++r)
#pragma unroll
        for (int q = 0; q < 4; ++q)
            buf[r][q].f = *(const float4*)(up0 + (size_t)r * JM + q * 8);

#pragma unroll
    for (int ii = 0; ii < 8; ++ii) {
        F4H cu[4];
#pragma unroll
        for (int q = 0; q < 4; ++q) cu[q] = buf[ii & 1][q];

        if (ii + 2 < 8) {
#pragma unroll
            for (int q = 0; q < 4; ++q)
                buf[ii & 1][q].f = *(const float4*)(up0 + (size_t)(ii + 2) * JM + q * 8);
        }

        // ap = sum_m vr[m]*u[m], 4 independent partial chains (depth 8)
        float p0 = 0.f, p1 = 0.f, p2 = 0.f, p3 = 0.f;
#pragma unroll
        for (int p = 0; p < 4; ++p) {
            const float2 u0 = __half22float2(cu[0].h2[p]);
            const float2 u1 = __half22float2(cu[1].h2[p]);
            const float2 u2 = __half22float2(cu[2].h2[p]);
            const float2 u3 = __half22float2(cu[3].h2[p]);
            p0 = fmaf(vr[p * 2],      u0.x, p0); p0 = fmaf(vr[p * 2 + 1],  u0.y, p0);
            p1 = fmaf(vr[8 + p * 2],  u1.x, p1); p1 = fmaf(vr[9 + p * 2],  u1.y, p1);
            p2 = fmaf(vr[16 + p * 2], u2.x, p2); p2 = fmaf(vr[17 + p * 2], u2.y, p2);
            p3 = fmaf(vr[24 + p * 2], u3.x, p3); p3 = fmaf(vr[25 + p * 2], u3.y, p3);
        }
        const float ap = (p0 + p1) + (p2 + p3);

        // softmax over 64 j, no max-subtraction (range-safe)
        const float e = __expf(ALPHA * ap);
        float se = e;
#pragma unroll
        for (int d = 1; d < 64; d <<= 1)
            se += __shfl_xor(se, d);
        const float c = e * (64.0f / se);

#pragma unroll
        for (int q = 0; q < 4; ++q)
#pragma unroll
            for (int p = 0; p < 4; ++p) {
                const float2 uf = __half22float2(cu[q].h2[p]);
                const int m = q * 8 + p * 2;
                acc[m]     = fmaf(c, uf.x, acc[m]);
                acc[m + 1] = fmaf(c, uf.y, acc[m + 1]);
            }
    }

    // cross-wave combine: 4 waves' acc -> one PART row (p = ig)
#pragma unroll
    for (int m = 0; m < 32; ++m) red[wv][l][m] = acc[m];
    __syncthreads();

    float s[8];
#pragma unroll
    for (int k = 0; k < 8; ++k) {
        const int jm = tid * 8 + k;
        const int j  = jm >> 5;
        const int m  = jm & 31;
        s[k] = (red[0][j][m] + red[1][j][m]) + (red[2][j][m] + red[3][j][m]);
    }
    float* dst = part + ((size_t)b * 64 + ig) * JM + tid * 8;
    *(float4*)(dst)     = make_float4(s[0], s[1], s[2], s[3]);
    *(float4*)(dst + 4) = make_float4(s[4], s[5], s[6], s[7]);
}

// ---------------------------------------------------------------------------
// reduce PART[b][p][jm] over p (4*PP partials) + squash.
// PP=64 for pass0's 256-partial PART; PP=16 for routes' 64-partial PART.
// ---------------------------------------------------------------------------
template <int PP>
__global__ __launch_bounds__(1024)
void reduce_squash(const float* __restrict__ part, float* __restrict__ v)
{
    __shared__ float red[4][256];
    const int tid = threadIdx.x;
    const int seg = tid >> 8;
    const int loc = tid & 255;
    const int b   = blockIdx.x >> 3;
    const int jmb = (blockIdx.x & 7) * 256;

    const float* p = part + ((size_t)b * (4 * PP) + seg * PP) * JM + jmb + loc;
    float s0 = 0.f, s1 = 0.f, s2 = 0.f, s3 = 0.f;
#pragma unroll 4
    for (int q = 0; q < PP; q += 4) {
        s0 += p[(size_t)(q + 0) * JM];
        s1 += p[(size_t)(q + 1) * JM];
        s2 += p[(size_t)(q + 2) * JM];
        s3 += p[(size_t)(q + 3) * JM];
    }
    red[seg][loc] = (s0 + s1) + (s2 + s3);
    __syncthreads();

    if (tid < 256) {
        const float s = (red[0][loc] + red[1][loc]) + (red[2][loc] + red[3][loc]);
        float sq = s * s;
#pragma unroll
        for (int k = 1; k < 32; k <<= 1) sq += __shfl_xor(sq, k);
        v[(size_t)b * JM + jmb + loc] =
            (sq / (1.0f + sq)) * (s * rsqrtf(sq + 1e-7f));
    }
}

__global__ __launch_bounds__(256)
void squash_kernel(const float* __restrict__ s, float* __restrict__ v)
{
    const int g = blockIdx.x * 256 + threadIdx.x;
    const float val = s[g];
    float sq = val * val;
#pragma unroll
    for (int k = 1; k < 32; k <<= 1) sq += __shfl_xor(sq, k);
    v[g] = (sq / (1.0f + sq)) * (val * rsqrtf(sq + 1e-7f));
}

// ---------------------------------------------------------------------------
extern "C" void kernel_launch(void* const* d_in, const int* in_sizes, int n_in,
                              void* d_out, int out_size, void* d_ws, size_t ws_size,
                              hipStream_t stream)
{
    const float* x = (const float*)d_in[0];
    const float* w = (const float*)d_in[1];
    float* out = (float*)d_out;
    float* ws  = (float*)d_ws;

    float* A0   = ws;                                   // fallback only
    float* V0   = A0 + (size_t)B_ * CI * CJ;
    float* V1   = V0 + (size_t)B_ * JM;
    float* PART = V1 + (size_t)B_ * JM;
    __half* U16 = (__half*)(PART + (size_t)B_ * NCH * JM);

    const size_t need_part =
        ((size_t)B_ * CI * CJ + 2 * (size_t)B_ * JM
         + (size_t)B_ * NCH * JM) * sizeof(float);
    const size_t need_full =
        need_part + (size_t)B_ * CI * JM * sizeof(__half);

    if (ws_size >= need_full) {
        pass0_full<<<256, 1024, 0, stream>>>(x, w, PART, U16);
        reduce_squash<64><<<128, 1024, 0, stream>>>(PART, V0);
        route_kernel<false><<<1024, 256, 0, stream>>>(U16, V0, nullptr, PART);
        reduce_squash<16><<<128, 1024, 0, stream>>>(PART, V1);
        route_kernel<true><<<1024, 256, 0, stream>>>(U16, V0, V1, PART);
        reduce_squash<16><<<128, 1024, 0, stream>>>(PART, out);
    } else if (ws_size >= need_part) {
        pass_kernel<0, false, false><<<512, 1024, 0, stream>>>(x, w, nullptr, nullptr, PART, nullptr);
        reduce_squash<64><<<128, 1024, 0, stream>>>(PART, V0);
        pass_kernel<1, false, false><<<512, 1024, 0, stream>>>(x, w, V0, A0, PART, nullptr);
        reduce_squash<64><<<128, 1024, 0, stream>>>(PART, V1);
        pass_kernel<2, false, false><<<512, 1024, 0, stream>>>(x, w, V1, A0, PART, nullptr);
        reduce_squash<64><<<128, 1024, 0, stream>>>(PART, out);
    } else {
        float* S0 = V1 + (size_t)B_ * JM;
        float* S1 = S0 + (size_t)B_ * JM;
        float* S2 = S1 + (size_t)B_ * JM;
        hipMemsetAsync(S0, 0, (size_t)3 * B_ * JM * sizeof(float), stream);
        pass_kernel<0, true, false><<<512, 1024, 0, stream>>>(x, w, nullptr, nullptr, S0, nullptr);
        squash_kernel<<<128, 256, 0, stream>>>(S0, V0);
        pass_kernel<1, true, false><<<512, 1024, 0, stream>>>(x, w, V0, A0, S1, nullptr);
        squash_kernel<<<128, 256, 0, stream>>>(S1, V1);
        pass_kernel<2, true, false><<<512, 1024, 0, stream>>>(x, w, V1, A0, S2, nullptr);
        squash_kernel<<<128, 256, 0, stream>>>(S2, out);
    }
}